// Round 1
// baseline (87.174 us; speedup 1.0000x reference)
//
#include <hip/hip_runtime.h>

// B=32, T=512, C=256, F=512.
// Reference softmax is over a size-1 axis -> att == 1.0 exactly, so
// out[b,c,f] = sum_t x[b,t,f], broadcast over c. context/W/b are dead.
// Pure bandwidth: read 33.5 MB (x) once + write 16.8 MB (out) once.
//
// Round-2 lesson: no cross-block communication (threadfence storm = 200 GB/s).
// Round-3 lesson (this version): previous grid was 256 blocks = 1 block/CU =
// 8 waves/CU (25% occupancy); kernel ran ~4.5x over its BW roofline.
// Shrink f-chunk 64->16 floats (64 B segments, still full cache sectors) so
// grid = 1024 blocks = 4 blocks/CU = 32 waves/CU (100% occupancy), and the
// two __syncthreads overlap across co-resident blocks.

#define BB 32
#define TT 512
#define CC 256
#define FF 512
#define F4 (FF / 4)      // 128 float4 per row
#define FC 32            // f-chunks per batch: 16 floats = 4 float4 each

__device__ __forceinline__ void acc4(float4& a, const float4& v) {
    a.x += v.x; a.y += v.y; a.z += v.z; a.w += v.w;
}

// grid = B * FC = 1024 blocks, 512 threads (4 blocks/CU, full 32 waves/CU).
// tid -> (g = tid>>2 in 0..127 : row group, f4l = tid&3 : float4 column).
__global__ __launch_bounds__(512, 8) void colsum_bcast(const float4* __restrict__ x4,
                                                       float4* __restrict__ out4) {
    __shared__ float4 lds[8][4];        // one partial per wave per column (512 B)

    const int tid  = threadIdx.x;
    const int f4l  = tid & 3;           // float4 column within the 64 B chunk
    const int g    = tid >> 2;          // 0..127 row group
    const int b    = blockIdx.x >> 5;   // / FC
    const int fc   = blockIdx.x & 31;
    const int lane = tid & 63;
    const int wave = tid >> 6;

    // ---- read: each thread sums 4 rows (g + 128k) of its float4 column ----
    const float4* xp = x4 + (size_t)b * TT * F4 + fc * 4 + f4l;
    float4 a = make_float4(0.f, 0.f, 0.f, 0.f);
#pragma unroll
    for (int k = 0; k < 4; ++k) {       // 4 independent loads in flight/thread
        float4 v = xp[(size_t)(g + 128 * k) * F4];
        acc4(a, v);
    }

    // ---- wave butterfly: reduce the 16 row-groups sharing this f4l column ----
#pragma unroll
    for (int off = 4; off < 64; off <<= 1) {
        a.x += __shfl_xor(a.x, off);
        a.y += __shfl_xor(a.y, off);
        a.z += __shfl_xor(a.z, off);
        a.w += __shfl_xor(a.w, off);
    }
    if (lane < 4) lds[wave][lane] = a;  // per-wave column partial
    __syncthreads();

    // ---- combine the 8 wave partials (4 threads, 7 adds each) ----
    if (tid < 4) {
        float4 s = lds[0][tid];
#pragma unroll
        for (int w = 1; w < 8; ++w) acc4(s, lds[w][tid]);
        lds[0][tid] = s;
    }
    __syncthreads();
    const float4 s = lds[0][f4l];       // broadcast read, no conflicts

    // ---- broadcast-store across the 256 c-rows of this (b, f-chunk) ----
    float4* op = out4 + (size_t)b * CC * F4 + fc * 4 + f4l;
#pragma unroll
    for (int k = 0; k < 2; ++k) {
        op[(size_t)(g + 128 * k) * F4] = s;
    }
}

extern "C" void kernel_launch(void* const* d_in, const int* in_sizes, int n_in,
                              void* d_out, int out_size, void* d_ws, size_t ws_size,
                              hipStream_t stream) {
    const float* x = (const float*)d_in[0];   // [B,T,F] fp32
    // d_in[1..3] (context, W, b) are dead: softmax over size-1 axis == 1.
    float* out = (float*)d_out;               // [B,C,F] fp32
    (void)d_ws; (void)ws_size;

    colsum_bcast<<<BB * FC, 512, 0, stream>>>((const float4*)x, (float4*)out);
}

// Round 2
// 85.882 us; speedup vs baseline: 1.0150x; 1.0150x over previous
//
#include <hip/hip_runtime.h>

// B=32, T=512, C=256, F=512.
// Reference softmax is over a size-1 axis -> att == 1.0 exactly, so
// out[b,c,f] = sum_t x[b,t,f], broadcast over c. context/W/b are dead.
// Pure bandwidth: read 33.5 MB (x) once + write 16.8 MB (out) once.
//
// Round-2 lesson: no cross-block threadfence communication (200 GB/s storm).
// Round-4 lesson (this version): column-sliced reads (64-256 B segments at
// 2 KB stride) ran at 1.4 TB/s regardless of occupancy -> DRAM row-buffer
// thrash. Restructure so every wave touches CONTIGUOUS memory:
//   K1: each block streams 32 contiguous rows (64 KB) -> 2 KB partial to ws.
//   K2: each block reduces 16 partials (L2-hot) -> broadcast 16 contiguous
//       2 KB c-rows. Stream ordering gives K1->K2 visibility (no fences).

#define BB 32
#define TT 512
#define CC 256
#define FF 512
#define F4 128           // float4 per row
#define NCH 16           // t-chunks per batch (32 rows each)
#define CG 16            // c-groups per batch (16 c-rows each)

__device__ __forceinline__ void acc4(float4& a, const float4& v) {
    a.x += v.x; a.y += v.y; a.z += v.z; a.w += v.w;
}

// Kernel 1: partial column sums. grid = BB*NCH = 512 blocks x 256 thr.
// Block (b, ch) reads rows [ch*32, ch*32+32) of x[b]: 64 KB contiguous,
// 4 KB per block-wide load instruction. Writes 2 KB partial.
__global__ __launch_bounds__(256) void colsum_partial(const float4* __restrict__ x4,
                                                      float4* __restrict__ part4) {
    __shared__ float4 lds[F4];          // 2 KB
    const int tid = threadIdx.x;
    const int c4  = tid & 127;          // float4 column 0..127
    const int rp  = tid >> 7;           // row parity 0/1
    const int b   = blockIdx.x >> 4;
    const int ch  = blockIdx.x & 15;

    const float4* xp = x4 + ((size_t)(b * TT + ch * 32 + rp) * F4) + c4;
    float4 a = make_float4(0.f, 0.f, 0.f, 0.f);
#pragma unroll
    for (int k = 0; k < 16; ++k) {      // 16 independent loads in flight
        acc4(a, xp[(size_t)(2 * k) * F4]);
    }

    if (rp == 1) lds[c4] = a;
    __syncthreads();
    if (rp == 0) {
        acc4(a, lds[c4]);
        part4[(size_t)(b * NCH + ch) * F4 + c4] = a;   // 2 KB contiguous
    }
}

// Kernel 2: reduce the 16 partials of batch b, broadcast to 16 c-rows.
// grid = BB*CG = 512 blocks x 256 thr. Reads 32 KB (L2-hot), writes 32 KB
// contiguous (4 KB per block-wide store instruction).
__global__ __launch_bounds__(256) void reduce_bcast(const float4* __restrict__ part4,
                                                    float4* __restrict__ out4) {
    __shared__ float4 lds[F4];          // 2 KB
    const int tid = threadIdx.x;
    const int c4  = tid & 127;
    const int rp  = tid >> 7;           // chunk parity 0/1
    const int b   = blockIdx.x >> 4;
    const int cg  = blockIdx.x & 15;

    const float4* pp = part4 + (size_t)(b * NCH + rp) * F4 + c4;
    float4 a = make_float4(0.f, 0.f, 0.f, 0.f);
#pragma unroll
    for (int k = 0; k < 8; ++k) {
        acc4(a, pp[(size_t)(2 * k) * F4]);
    }

    if (rp == 1) lds[c4] = a;
    __syncthreads();
    if (rp == 0) {
        acc4(a, lds[c4]);
        lds[c4] = a;                    // only the rp==0 owner touches lds[c4] here
    }
    __syncthreads();
    const float4 s = lds[c4];

    float4* op = out4 + (size_t)(b * CC + cg * 16 + rp) * F4 + c4;
#pragma unroll
    for (int k = 0; k < 8; ++k) {       // 16 rows total: 2 contiguous rows/iter
        op[(size_t)(2 * k) * F4] = s;
    }
}

extern "C" void kernel_launch(void* const* d_in, const int* in_sizes, int n_in,
                              void* d_out, int out_size, void* d_ws, size_t ws_size,
                              hipStream_t stream) {
    const float* x = (const float*)d_in[0];   // [B,T,F] fp32
    // d_in[1..3] (context, W, b) are dead: softmax over size-1 axis == 1.
    float* out = (float*)d_out;               // [B,C,F] fp32

    float4* part = (float4*)d_ws;             // BB*NCH*FF floats = 1 MB
    colsum_partial<<<BB * NCH, 256, 0, stream>>>((const float4*)x, part);
    reduce_bcast<<<BB * CG, 256, 0, stream>>>(part, (float4*)out);
}